// Round 7
// baseline (154.768 us; speedup 1.0000x reference)
//
#include <hip/hip_runtime.h>
#include <hip/hip_bf16.h>

// Problem constants (fixed by the reference).
#define BSZ 4
#define SEQ 512
#define DMODEL 512
#define NHEAD 8
#define DKH 64
#define EPSLN 1e-6f

typedef short bf16x8 __attribute__((ext_vector_type(8)));
typedef float f32x4 __attribute__((ext_vector_type(4)));

// fp32 -> bf16 round-to-nearest-even
static __device__ __forceinline__ short f2bf(float x) {
  unsigned u = __builtin_bit_cast(unsigned, x);
  u = (u + 0x7FFFu + ((u >> 16) & 1u)) >> 16;
  return (short)u;
}
static __device__ __forceinline__ bf16x8 cvt8(float4 a, float4 b) {
  bf16x8 r;
  r[0] = f2bf(a.x); r[1] = f2bf(a.y); r[2] = f2bf(a.z); r[3] = f2bf(a.w);
  r[4] = f2bf(b.x); r[5] = f2bf(b.y); r[6] = f2bf(b.z); r[7] = f2bf(b.w);
  return r;
}
static __device__ __forceinline__ unsigned pk2(float a, float b) {
  return (unsigned)(unsigned short)f2bf(a) |
         ((unsigned)(unsigned short)f2bf(b) << 16);
}
// async 16B/lane global -> LDS (lds dest = wave-uniform base + lane*16)
static __device__ __forceinline__ void async_cp16(const void* g, void* l) {
  __builtin_amdgcn_global_load_lds(
      (const __attribute__((address_space(1))) unsigned int*)g,
      (__attribute__((address_space(3))) unsigned int*)l, 16, 0, 0);
}

// ---------------------------------------------------------------------------
// Prep (one launch): blocks 0..1535 cast q/k/v fp32->bf16; blocks 1536..1791
// transpose+cast the four W's to bf16 [N][K].
// ---------------------------------------------------------------------------
__global__ __launch_bounds__(256) void prep_kernel(
    const float* __restrict__ q, const float* __restrict__ k,
    const float* __restrict__ v, short* __restrict__ qb,
    short* __restrict__ kb, short* __restrict__ vb,
    const float* __restrict__ Wq, const float* __restrict__ Wk,
    const float* __restrict__ Wv, const float* __restrict__ Wo,
    short* __restrict__ Wqt, short* __restrict__ Wkt,
    short* __restrict__ Wvt, short* __restrict__ Wot) {
  __shared__ float T[64][65];
  const int bx = blockIdx.x;
  if (bx < 1536) {
    const int which = bx >> 9, blk = bx & 511;
    const float* s; short* d;
    switch (which) {
      case 0: s = q; d = qb; break;
      case 1: s = k; d = kb; break;
      default: s = v; d = vb; break;
    }
    const size_t idx = (size_t)blk * 2048 + (size_t)threadIdx.x * 8;
    float4 a = *(const float4*)&s[idx];
    float4 b = *(const float4*)&s[idx + 4];
    *(bf16x8*)&d[idx] = cvt8(a, b);
    return;
  }
  const int r = bx - 1536;
  const int mat = r >> 6, m = r & 63;
  const int k0 = (m & 7) * 64, n0 = (m >> 3) * 64;
  const float* src; short* dst;
  switch (mat) {
    case 0: src = Wq; dst = Wqt; break;
    case 1: src = Wk; dst = Wkt; break;
    case 2: src = Wv; dst = Wvt; break;
    default: src = Wo; dst = Wot; break;
  }
  const int tid = threadIdx.x;
  const int n4 = (tid & 15) * 4, kk = tid >> 4;
#pragma unroll
  for (int p = 0; p < 4; ++p) {
    float4 w4 = *(const float4*)&src[(size_t)(k0 + kk + p * 16) * DMODEL + n0 + n4];
    T[kk + p * 16][n4 + 0] = w4.x;
    T[kk + p * 16][n4 + 1] = w4.y;
    T[kk + p * 16][n4 + 2] = w4.z;
    T[kk + p * 16][n4 + 3] = w4.w;
  }
  __syncthreads();
  const int k4 = (tid & 15) * 4;
#pragma unroll
  for (int p = 0; p < 4; ++p) {
    const int nn = (tid >> 4) + p * 16;
    float x0 = T[k4 + 0][nn], x1 = T[k4 + 1][nn];
    float x2 = T[k4 + 2][nn], x3 = T[k4 + 3][nn];
    uint2 u; u.x = pk2(x0, x1); u.y = pk2(x2, x3);
    *(uint2*)&dst[(size_t)(n0 + nn) * DMODEL + k0 + k4] = u;
  }
}

// ---------------------------------------------------------------------------
// m97-style GEMM body: C[128x128] = A(bf16 [M][512]) @ Wt(bf16 [N][512])^T
// + bias. Rotating double-buffer, one barrier per k-step.
// ---------------------------------------------------------------------------
__device__ __forceinline__ void gemm_body(
    const short* __restrict__ A, const short* __restrict__ Wt,
    const float* __restrict__ bias, void* __restrict__ out, int omode) {
  __shared__ short As[2][128 * 32];
  __shared__ short Bs[2][128 * 32];
  const int tid = threadIdx.x;
  const int w = tid >> 6, lane = tid & 63;
  const int l15 = lane & 15, q = lane >> 4;
  const int wm = w >> 1, wn = w & 1;
  const int bn = blockIdx.x * 128, bm = blockIdx.y * 128;
  const int wu = __builtin_amdgcn_readfirstlane(w);
  const int srow = wu * 16 + (lane >> 2);
  const int sch = lane & 3;

  f32x4 acc[4][4] = {};

#define GSTAGE(k0, buf)                                                      \
  {                                                                          \
    const short* ga0 = A + (size_t)(bm + srow) * 512 + (k0) + sch * 8;       \
    const short* ga1 = A + (size_t)(bm + srow + 64) * 512 + (k0) + sch * 8;  \
    const short* gb0 = Wt + (size_t)(bn + srow) * 512 + (k0) + sch * 8;      \
    const short* gb1 = Wt + (size_t)(bn + srow + 64) * 512 + (k0) + sch * 8; \
    async_cp16(ga0, &As[buf][wu * 512]);                                     \
    async_cp16(ga1, &As[buf][(4 + wu) * 512]);                               \
    async_cp16(gb0, &Bs[buf][wu * 512]);                                     \
    async_cp16(gb1, &Bs[buf][(4 + wu) * 512]);                               \
  }

  GSTAGE(0, 0);
  for (int ks = 0; ks < 16; ++ks) {
    __syncthreads();
    if (ks < 15) GSTAGE((ks + 1) * 32, (ks + 1) & 1);
    const short* a = As[ks & 1];
    const short* bsh = Bs[ks & 1];
    bf16x8 af[4], bfr[4];
#pragma unroll
    for (int mt = 0; mt < 4; ++mt)
      af[mt] = *(const bf16x8*)&a[(wm * 64 + mt * 16 + l15) * 32 + q * 8];
#pragma unroll
    for (int nt = 0; nt < 4; ++nt)
      bfr[nt] = *(const bf16x8*)&bsh[(wn * 64 + nt * 16 + l15) * 32 + q * 8];
#pragma unroll
    for (int mt = 0; mt < 4; ++mt)
#pragma unroll
      for (int nt = 0; nt < 4; ++nt)
        acc[mt][nt] = __builtin_amdgcn_mfma_f32_16x16x32_bf16(
            af[mt], bfr[nt], acc[mt][nt], 0, 0, 0);
  }
#undef GSTAGE

  float bv[4];
#pragma unroll
  for (int nt = 0; nt < 4; ++nt) bv[nt] = bias[bn + wn * 64 + nt * 16 + l15];
#pragma unroll
  for (int mt = 0; mt < 4; ++mt)
#pragma unroll
    for (int nt = 0; nt < 4; ++nt) {
      const int col = bn + wn * 64 + nt * 16 + l15;
#pragma unroll
      for (int r = 0; r < 4; ++r) {
        const int row = bm + wm * 64 + mt * 16 + q * 4 + r;
        const float val = acc[mt][nt][r] + bv[nt];
        if (omode == 0) {
          ((float*)out)[(size_t)row * 512 + col] = val;
        } else if (omode == 1) {
          ((short*)out)[(size_t)row * 512 + col] = f2bf(val);
        } else {
          const int cc = row >> 9, j = row & 511;
          const int hh = col >> 6, d = col & 63;
          ((short*)out)[(((size_t)(cc * 8 + hh) * 64 + d) << 9) + j] = f2bf(val);
        }
      }
    }
}

__global__ __launch_bounds__(256, 2) void proj_gemm(
    const short* qb, const short* kb, const short* vb,
    const short* Wqt, const short* Wkt, const short* Wvt,
    const float* bq, const float* bk, const float* bvs,
    float* Qp, short* Kb, short* Vt) {
  const short* A; const short* Wt; const float* bias; void* out; int omode;
  switch (blockIdx.z) {
    case 0: A = qb; Wt = Wqt; bias = bq; out = Qp; omode = 0; break;
    case 1: A = kb; Wt = Wkt; bias = bk; out = Kb; omode = 1; break;
    default: A = vb; Wt = Wvt; bias = bvs; out = Vt; omode = 2; break;
  }
  gemm_body(A, Wt, bias, out, omode);
}

__global__ __launch_bounds__(256, 2) void out_gemm(
    const short* Hc, const short* Wot, const float* bo, float* out) {
  gemm_body(Hc, Wot, bo, out, 0);
}

// ---------------------------------------------------------------------------
// Fused attention v3: 64 q-rows per block -> 256 blocks (1/CU). Halves the
// total L2->LDS staging traffic vs R6 (each block still stages its head's
// full K/V = 512 KB, but there are half as many blocks) and doubles per-
// phase compute (16 MFMA/wave) so the post-barrier staging latency is
// covered by compute. 4 waves; wave w owns rows i0+w*16..+15 for the WHOLE
// j/K range -> no cross-wave K-split, no xch buffer, full-parallel epilogue.
// Per jt (8 j-tiles), 4 phases (rotating 2x16KB double-buffer, one barrier
// each): ph2=0 QK^T c01 [stage K c23]; ph2=1 QK^T c23, R->Rs [stage V c01];
// ph2=2 R@V c01 [stage V c23]; ph2=3 R@V c23 [stage K(jt+1) c01].
// All acc[] indices compile-time (R3 lesson: runtime idx => scratch spill).
// LDS: 32K stage + 9.2K Rs = 41.2 KB. ~170 VGPR -> __launch_bounds__(256,1).
// ---------------------------------------------------------------------------
__global__ __launch_bounds__(256, 1) void attn3_kernel(
    const float* __restrict__ Qp, const short* __restrict__ Kb,
    const short* __restrict__ Vt, const float* __restrict__ alpha,
    const float* __restrict__ beta, short* __restrict__ Hc) {
  __shared__ __align__(16) short Stage[2][2 * 4096];  // 2 bufs x 2 tiles
  __shared__ __align__(16) short Rs[64][72];

  const int bx = blockIdx.x;
  const int h = bx & 7;            // XCD-affinity (harmless if mapping differs)
  const int b = (bx >> 3) & 3;
  const int it = bx >> 5;          // 0..7
  const int i0 = it * 64;
  const int tid = threadIdx.x;
  const int w = tid >> 6, lane = tid & 63;
  const int l15 = lane & 15, q = lane >> 4;
  const int wu = __builtin_amdgcn_readfirstlane(w);

  // Q A-fragments (rows i0 + w*16 + l15), fp32 -> bf16, reused throughout.
  const float* qrow =
      Qp + (size_t)(b * SEQ + i0 + w * 16 + l15) * DMODEL + h * DKH;
  const bf16x8 aq0 = cvt8(*(const float4*)(qrow + q * 8),
                          *(const float4*)(qrow + q * 8 + 4));
  const bf16x8 aq1 = cvt8(*(const float4*)(qrow + 32 + q * 8),
                          *(const float4*)(qrow + 32 + q * 8 + 4));

  // Staging lane constants: issue0 rows 0..31, issue1 rows 32..63; physical
  // slot lane&7 holds logical chunk (lane&7)^(row&7), row&7 = lane>>3.
  const int srow0 = wu * 8 + (lane >> 3);
  const int scol = (lane & 7) ^ (lane >> 3);

  const short* kbase_h = Kb + h * DKH;
  const short* vbase_h = Vt + (((size_t)h * DKH) << 9);

#define STG1(g0, rs, buf, tslot)                                          \
  {                                                                       \
    async_cp16((g0) + (size_t)srow0 * (rs) + scol * 8,                    \
               &Stage[buf][(tslot) * 4096 + wu * 512]);                   \
    async_cp16((g0) + (size_t)(srow0 + 32) * (rs) + scol * 8,             \
               &Stage[buf][(tslot) * 4096 + (4 + wu) * 512]);             \
  }
#define KTILE(c, j0) (kbase_h + ((size_t)((c) * SEQ) + (j0)) * DMODEL)
#define VTILE(c, j0) (vbase_h + (((size_t)((c) * NHEAD * DKH)) << 9) + (j0))

  f32x4 acc[4][4] = {};          // R@V partials [c][nt] — static idx only
  float sacc[4][4], ebb[4][4];   // fenmu accum / diagonal exps [jchunk][r]

  // prologue: stage K c0,c1 of jt=0 into buf 0
  STG1(KTILE(0, 0), DMODEL, 0, 0);
  STG1(KTILE(1, 0), DMODEL, 0, 1);

  for (int jt = 0; jt < 8; ++jt) {
    const int j0 = jt * 64;
    bf16x8 ar0, ar1;  // R A-fragments for this jt (loaded at ph2==2)
#pragma unroll
    for (int ph2 = 0; ph2 < 4; ++ph2) {
      __syncthreads();  // drains stage(jt,ph2); frees buf (ph2^1)
      const int buf = ph2 & 1, nbuf = buf ^ 1;
      // ---- stage next phase (overlaps this phase's compute) ----
      if (ph2 == 0) {
        STG1(KTILE(2, j0), DMODEL, nbuf, 0);
        STG1(KTILE(3, j0), DMODEL, nbuf, 1);
      } else if (ph2 == 1) {
        STG1(VTILE(0, j0), SEQ, nbuf, 0);
        STG1(VTILE(1, j0), SEQ, nbuf, 1);
      } else if (ph2 == 2) {
        STG1(VTILE(2, j0), SEQ, nbuf, 0);
        STG1(VTILE(3, j0), SEQ, nbuf, 1);
      } else if (jt < 7) {
        STG1(KTILE(0, j0 + 64), DMODEL, nbuf, 0);
        STG1(KTILE(1, j0 + 64), DMODEL, nbuf, 1);
      }
      if (ph2 < 2) {
        // ---- QK^T for c = ph2*2+ct over all 64 j of this tile ----
        if (ph2 == 0) {
#pragma unroll
          for (int t = 0; t < 4; ++t)
#pragma unroll
            for (int r = 0; r < 4; ++r) { sacc[t][r] = 0.0f; ebb[t][r] = 0.0f; }
        }
#pragma unroll
        for (int ct = 0; ct < 2; ++ct) {
          const int c = ph2 * 2 + ct;
          const short* S = &Stage[buf][ct * 4096];
#pragma unroll
          for (int ntl = 0; ntl < 4; ++ntl) {
            const int row = ntl * 16 + l15;   // j within tile
            const int p0 = q ^ (l15 & 7);     // physical chunk (logical q)
            bf16x8 b0 = *(const bf16x8*)&S[row * 64 + p0 * 8];
            bf16x8 b1 = *(const bf16x8*)&S[row * 64 + (p0 ^ 4) * 8];
            f32x4 s = {};
            s = __builtin_amdgcn_mfma_f32_16x16x32_bf16(aq0, b0, s, 0, 0, 0);
            s = __builtin_amdgcn_mfma_f32_16x16x32_bf16(aq1, b1, s, 0, 0, 0);
#pragma unroll
            for (int r = 0; r < 4; ++r) {
              const float e = __expf(s[r]);
              sacc[ntl][r] += e;
              ebb[ntl][r] = (c == b) ? e : ebb[ntl][r];
            }
          }
        }
        if (ph2 == 1) {  // fenmu complete -> R tile (bf16), own rows only
#pragma unroll
          for (int ntl = 0; ntl < 4; ++ntl)
#pragma unroll
            for (int r = 0; r < 4; ++r)
              Rs[w * 16 + q * 4 + r][ntl * 16 + l15] =
                  f2bf(ebb[ntl][r] / (8.0f * sacc[ntl][r]));
        }
      } else {
        // ---- R@V partial for c = (ph2-2)*2+ct (compile-time) ----
        if (ph2 == 2) {  // own rows: written by this wave at ph2==1
          ar0 = *(const bf16x8*)&Rs[w * 16 + l15][q * 8];
          ar1 = *(const bf16x8*)&Rs[w * 16 + l15][32 + q * 8];
        }
#pragma unroll
        for (int ct = 0; ct < 2; ++ct) {
          const int c = (ph2 - 2) * 2 + ct;
          const short* S = &Stage[buf][ct * 4096];
#pragma unroll
          for (int nt = 0; nt < 4; ++nt) {
            const int row = nt * 16 + l15;    // d within tile
            const int p0 = q ^ (l15 & 7);
            bf16x8 bv0 = *(const bf16x8*)&S[row * 64 + p0 * 8];
            bf16x8 bv1 = *(const bf16x8*)&S[row * 64 + (p0 ^ 4) * 8];
            acc[c][nt] = __builtin_amdgcn_mfma_f32_16x16x32_bf16(
                ar0, bv0, acc[c][nt], 0, 0, 0);
            acc[c][nt] = __builtin_amdgcn_mfma_f32_16x16x32_bf16(
                ar1, bv1, acc[c][nt], 0, 0, 0);
          }
        }
      }
    }
  }
#undef STG1
#undef KTILE
#undef VTILE

  // ---- epilogue: every wave handles its own 16 rows ----
  float al[4], be[4];
#pragma unroll
  for (int nt = 0; nt < 4; ++nt) {
    al[nt] = alpha[nt * 16 + l15];
    be[nt] = beta[nt * 16 + l15];
  }
  float hacc[4][4] = {};  // [r][nt]
#pragma unroll
  for (int c = 0; c < BSZ; ++c) {
#pragma unroll
    for (int r = 0; r < 4; ++r) {
      float e0 = __expf(acc[c][0][r]), e1 = __expf(acc[c][1][r]);
      float e2 = __expf(acc[c][2][r]), e3 = __expf(acc[c][3][r]);
      float es = e0 + e1 + e2 + e3;
#pragma unroll
      for (int m = 8; m >= 1; m >>= 1) es += __shfl_xor(es, m);
      const float inv = 1.0f / es;
      const float d0 = e0 * inv - 0.015625f, d1 = e1 * inv - 0.015625f;
      const float d2 = e2 * inv - 0.015625f, d3 = e3 * inv - 0.015625f;
      float sq = d0 * d0 + d1 * d1 + d2 * d2 + d3 * d3;
#pragma unroll
      for (int m = 8; m >= 1; m >>= 1) sq += __shfl_xor(sq, m);
      const float rs = 1.0f / (sqrtf(sq * (1.0f / 63.0f)) + EPSLN);
      hacc[r][0] += al[0] * d0 * rs + be[0];
      hacc[r][1] += al[1] * d1 * rs + be[1];
      hacc[r][2] += al[2] * d2 * rs + be[2];
      hacc[r][3] += al[3] * d3 * rs + be[3];
    }
  }
#pragma unroll
  for (int r = 0; r < 4; ++r) {
    const size_t rowoff =
        (size_t)(b * SEQ + i0 + w * 16 + q * 4 + r) * DMODEL + h * DKH;
#pragma unroll
    for (int nt = 0; nt < 4; ++nt) {
      const int d = nt * 16 + l15;
      const float o = hacc[r][nt] + 4.0f * Qp[rowoff + d];
      Hc[rowoff + d] = f2bf(o);
    }
  }
}

// ---------------------------------------------------------------------------
extern "C" void kernel_launch(void* const* d_in, const int* in_sizes, int n_in,
                              void* d_out, int out_size, void* d_ws,
                              size_t ws_size, hipStream_t stream) {
  (void)in_sizes; (void)n_in; (void)out_size; (void)ws_size;
  const float* q = (const float*)d_in[0];
  const float* k = (const float*)d_in[1];
  const float* v = (const float*)d_in[2];
  const float* Wq = (const float*)d_in[3];
  const float* bq = (const float*)d_in[4];
  const float* Wk = (const float*)d_in[5];
  const float* bk = (const float*)d_in[6];
  const float* Wv = (const float*)d_in[7];
  const float* bv = (const float*)d_in[8];
  const float* Wo = (const float*)d_in[9];
  const float* bo = (const float*)d_in[10];
  const float* alpha = (const float*)d_in[11];
  const float* beta = (const float*)d_in[12];
  float* out = (float*)d_out;

  char* wsb = (char*)d_ws;
  short* qb = (short*)(wsb);
  short* kb = (short*)(wsb + (2u << 20));
  short* vb = (short*)(wsb + (4u << 20));
  float* Qp = (float*)(wsb + (6u << 20));
  short* Kb = (short*)(wsb + (10u << 20));
  short* Vtg = (short*)(wsb + (12u << 20));
  short* Hc = (short*)(wsb + (14u << 20));
  short* Wqt = (short*)(wsb + (16u << 20));
  short* Wkt = (short*)(wsb + (16u << 20) + (512u << 10));
  short* Wvt = (short*)(wsb + (17u << 20));
  short* Wot = (short*)(wsb + (17u << 20) + (512u << 10));

  prep_kernel<<<dim3(1792), 256, 0, stream>>>(q, k, v, qb, kb, vb,
                                              Wq, Wk, Wv, Wo,
                                              Wqt, Wkt, Wvt, Wot);
  proj_gemm<<<dim3(4, 16, 3), 256, 0, stream>>>(qb, kb, vb, Wqt, Wkt, Wvt,
                                                bq, bk, bv, Qp, Kb, Vtg);
  attn3_kernel<<<dim3(256), 256, 0, stream>>>(Qp, Kb, Vtg, alpha, beta, Hc);
  out_gemm<<<dim3(4, 16), 256, 0, stream>>>(Hc, Wot, bo, out);
}

// Round 8
// 147.134 us; speedup vs baseline: 1.0519x; 1.0519x over previous
//
#include <hip/hip_runtime.h>
#include <hip/hip_bf16.h>

// Problem constants (fixed by the reference).
#define BSZ 4
#define SEQ 512
#define DMODEL 512
#define NHEAD 8
#define DKH 64
#define EPSLN 1e-6f

typedef short bf16x8 __attribute__((ext_vector_type(8)));
typedef float f32x4 __attribute__((ext_vector_type(4)));

// fp32 -> bf16 round-to-nearest-even
static __device__ __forceinline__ short f2bf(float x) {
  unsigned u = __builtin_bit_cast(unsigned, x);
  u = (u + 0x7FFFu + ((u >> 16) & 1u)) >> 16;
  return (short)u;
}
static __device__ __forceinline__ bf16x8 cvt8(float4 a, float4 b) {
  bf16x8 r;
  r[0] = f2bf(a.x); r[1] = f2bf(a.y); r[2] = f2bf(a.z); r[3] = f2bf(a.w);
  r[4] = f2bf(b.x); r[5] = f2bf(b.y); r[6] = f2bf(b.z); r[7] = f2bf(b.w);
  return r;
}
static __device__ __forceinline__ unsigned pk2(float a, float b) {
  return (unsigned)(unsigned short)f2bf(a) |
         ((unsigned)(unsigned short)f2bf(b) << 16);
}
// async 16B/lane global -> LDS (lds dest = wave-uniform base + lane*16)
static __device__ __forceinline__ void async_cp16(const void* g, void* l) {
  __builtin_amdgcn_global_load_lds(
      (const __attribute__((address_space(1))) unsigned int*)g,
      (__attribute__((address_space(3))) unsigned int*)l, 16, 0, 0);
}

// ---------------------------------------------------------------------------
// Prep (one launch): blocks 0..1535 cast q/k/v fp32->bf16; blocks 1536..1791
// transpose+cast the four W's to bf16 [N][K].
// ---------------------------------------------------------------------------
__global__ __launch_bounds__(256) void prep_kernel(
    const float* __restrict__ q, const float* __restrict__ k,
    const float* __restrict__ v, short* __restrict__ qb,
    short* __restrict__ kb, short* __restrict__ vb,
    const float* __restrict__ Wq, const float* __restrict__ Wk,
    const float* __restrict__ Wv, const float* __restrict__ Wo,
    short* __restrict__ Wqt, short* __restrict__ Wkt,
    short* __restrict__ Wvt, short* __restrict__ Wot) {
  __shared__ float T[64][65];
  const int bx = blockIdx.x;
  if (bx < 1536) {
    const int which = bx >> 9, blk = bx & 511;
    const float* s; short* d;
    switch (which) {
      case 0: s = q; d = qb; break;
      case 1: s = k; d = kb; break;
      default: s = v; d = vb; break;
    }
    const size_t idx = (size_t)blk * 2048 + (size_t)threadIdx.x * 8;
    float4 a = *(const float4*)&s[idx];
    float4 b = *(const float4*)&s[idx + 4];
    *(bf16x8*)&d[idx] = cvt8(a, b);
    return;
  }
  const int r = bx - 1536;
  const int mat = r >> 6, m = r & 63;
  const int k0 = (m & 7) * 64, n0 = (m >> 3) * 64;
  const float* src; short* dst;
  switch (mat) {
    case 0: src = Wq; dst = Wqt; break;
    case 1: src = Wk; dst = Wkt; break;
    case 2: src = Wv; dst = Wvt; break;
    default: src = Wo; dst = Wot; break;
  }
  const int tid = threadIdx.x;
  const int n4 = (tid & 15) * 4, kk = tid >> 4;
#pragma unroll
  for (int p = 0; p < 4; ++p) {
    float4 w4 = *(const float4*)&src[(size_t)(k0 + kk + p * 16) * DMODEL + n0 + n4];
    T[kk + p * 16][n4 + 0] = w4.x;
    T[kk + p * 16][n4 + 1] = w4.y;
    T[kk + p * 16][n4 + 2] = w4.z;
    T[kk + p * 16][n4 + 3] = w4.w;
  }
  __syncthreads();
  const int k4 = (tid & 15) * 4;
#pragma unroll
  for (int p = 0; p < 4; ++p) {
    const int nn = (tid >> 4) + p * 16;
    float x0 = T[k4 + 0][nn], x1 = T[k4 + 1][nn];
    float x2 = T[k4 + 2][nn], x3 = T[k4 + 3][nn];
    uint2 u; u.x = pk2(x0, x1); u.y = pk2(x2, x3);
    *(uint2*)&dst[(size_t)(n0 + nn) * DMODEL + k0 + k4] = u;
  }
}

// ---------------------------------------------------------------------------
// m97-style GEMM body: C[128x128] = A(bf16 [M][512]) @ Wt(bf16 [N][512])^T
// + bias. Rotating double-buffer, one barrier per k-step.
// LDS tiles are 128 rows x 32 k (64 B = 4x16B chunks per row). Physical
// chunk c holds logical chunk c ^ ((row>>1)&3): staging still fetches one
// contiguous 64B row segment per 4 lanes (coalescing intact, order permuted)
// and fragment ds_read_b128 spreads over (row&1)x(4 chunks) = 8 bank-groups
// = all 32 banks at 2-way (free). Without this the reads were 8-way
// conflicted (addr%128B depended only on row&1 and chunk).
// ---------------------------------------------------------------------------
__device__ __forceinline__ void gemm_body(
    const short* __restrict__ A, const short* __restrict__ Wt,
    const float* __restrict__ bias, void* __restrict__ out, int omode) {
  __shared__ short As[2][128 * 32];
  __shared__ short Bs[2][128 * 32];
  const int tid = threadIdx.x;
  const int w = tid >> 6, lane = tid & 63;
  const int l15 = lane & 15, q = lane >> 4;
  const int wm = w >> 1, wn = w & 1;
  const int bn = blockIdx.x * 128, bm = blockIdx.y * 128;
  const int wu = __builtin_amdgcn_readfirstlane(w);
  const int srow = wu * 16 + (lane >> 2);               // staging row (issue 0)
  const int sch = (lane & 3) ^ ((srow >> 1) & 3);       // swizzled fetch chunk
  // (srow+64)>>1 & 3 == (srow>>1)&3  (64/2 = 32, mult of 4) -> same swizzle.

  f32x4 acc[4][4] = {};

#define GSTAGE(k0, buf)                                                      \
  {                                                                          \
    const short* ga0 = A + (size_t)(bm + srow) * 512 + (k0) + sch * 8;       \
    const short* ga1 = A + (size_t)(bm + srow + 64) * 512 + (k0) + sch * 8;  \
    const short* gb0 = Wt + (size_t)(bn + srow) * 512 + (k0) + sch * 8;      \
    const short* gb1 = Wt + (size_t)(bn + srow + 64) * 512 + (k0) + sch * 8; \
    async_cp16(ga0, &As[buf][wu * 512]);                                     \
    async_cp16(ga1, &As[buf][(4 + wu) * 512]);                               \
    async_cp16(gb0, &Bs[buf][wu * 512]);                                     \
    async_cp16(gb1, &Bs[buf][(4 + wu) * 512]);                               \
  }

  GSTAGE(0, 0);
  for (int ks = 0; ks < 16; ++ks) {
    __syncthreads();
    if (ks < 15) GSTAGE((ks + 1) * 32, (ks + 1) & 1);
    const short* a = As[ks & 1];
    const short* bsh = Bs[ks & 1];
    bf16x8 af[4], bfr[4];
#pragma unroll
    for (int mt = 0; mt < 4; ++mt) {
      const int ra = wm * 64 + mt * 16 + l15;
      af[mt] = *(const bf16x8*)&a[ra * 32 + (q ^ ((ra >> 1) & 3)) * 8];
    }
#pragma unroll
    for (int nt = 0; nt < 4; ++nt) {
      const int rb = wn * 64 + nt * 16 + l15;
      bfr[nt] = *(const bf16x8*)&bsh[rb * 32 + (q ^ ((rb >> 1) & 3)) * 8];
    }
#pragma unroll
    for (int mt = 0; mt < 4; ++mt)
#pragma unroll
      for (int nt = 0; nt < 4; ++nt)
        acc[mt][nt] = __builtin_amdgcn_mfma_f32_16x16x32_bf16(
            af[mt], bfr[nt], acc[mt][nt], 0, 0, 0);
  }
#undef GSTAGE

  float bv[4];
#pragma unroll
  for (int nt = 0; nt < 4; ++nt) bv[nt] = bias[bn + wn * 64 + nt * 16 + l15];
#pragma unroll
  for (int mt = 0; mt < 4; ++mt)
#pragma unroll
    for (int nt = 0; nt < 4; ++nt) {
      const int col = bn + wn * 64 + nt * 16 + l15;
#pragma unroll
      for (int r = 0; r < 4; ++r) {
        const int row = bm + wm * 64 + mt * 16 + q * 4 + r;
        const float val = acc[mt][nt][r] + bv[nt];
        if (omode == 0) {
          ((float*)out)[(size_t)row * 512 + col] = val;
        } else if (omode == 1) {
          ((short*)out)[(size_t)row * 512 + col] = f2bf(val);
        } else {
          const int cc = row >> 9, j = row & 511;
          const int hh = col >> 6, d = col & 63;
          ((short*)out)[(((size_t)(cc * 8 + hh) * 64 + d) << 9) + j] = f2bf(val);
        }
      }
    }
}

__global__ __launch_bounds__(256, 3) void proj_gemm(
    const short* qb, const short* kb, const short* vb,
    const short* Wqt, const short* Wkt, const short* Wvt,
    const float* bq, const float* bk, const float* bvs,
    float* Qp, short* Kb, short* Vt) {
  const short* A; const short* Wt; const float* bias; void* out; int omode;
  switch (blockIdx.z) {
    case 0: A = qb; Wt = Wqt; bias = bq; out = Qp; omode = 0; break;
    case 1: A = kb; Wt = Wkt; bias = bk; out = Kb; omode = 1; break;
    default: A = vb; Wt = Wvt; bias = bvs; out = Vt; omode = 2; break;
  }
  gemm_body(A, Wt, bias, out, omode);
}

__global__ __launch_bounds__(256, 3) void out_gemm(
    const short* Hc, const short* Wot, const float* bo, float* out) {
  gemm_body(Hc, Wot, bo, out, 0);
}

// ---------------------------------------------------------------------------
// Fused attention (R6 structure — proven fastest). 512 blocks (2-3/CU:
// co-residency hides the per-phase barrier drain; R7 showed 1 block/CU
// doubles the time). 32 q-rows/block; 4 waves (wi = i-half, wj = K-split).
// Per jt (8 j-tiles), 4 phases, rotating 2x16KB double-buffer, one barrier
// each; stage(p+1) issued right after the barrier overlaps compute(p).
// All acc[] indices compile-time (R3 lesson: runtime idx => scratch spill).
// Epilogue: cross-wj reduction via xch, softmax(64) + LN, sum c, +4*qh.
// LDS: 32K stage + 4.6K Rs + 8K xch = 44.6 KB.
// ---------------------------------------------------------------------------
__global__ __launch_bounds__(256, 3) void attn2_kernel(
    const float* __restrict__ Qp, const short* __restrict__ Kb,
    const short* __restrict__ Vt, const float* __restrict__ alpha,
    const float* __restrict__ beta, short* __restrict__ Hc) {
  __shared__ __align__(16) short Stage[2][2 * 4096];  // 2 bufs x 2 tiles
  __shared__ __align__(16) short Rs[32][72];
  __shared__ __align__(16) float xch[16 * 128];

  const int bx = blockIdx.x;
  const int h = bx & 7;
  const int b = (bx >> 3) & 3;
  const int it = bx >> 5;
  const int i0 = it * 32;
  const int tid = threadIdx.x;
  const int w = tid >> 6, lane = tid & 63;
  const int l15 = lane & 15, q = lane >> 4;
  const int wi = w >> 1, wj = w & 1;
  const int wu = __builtin_amdgcn_readfirstlane(w);

  // Q A-fragments (rows i0 + wi*16 + l15), fp32 -> bf16, reused throughout.
  const float* qrow =
      Qp + (size_t)(b * SEQ + i0 + wi * 16 + l15) * DMODEL + h * DKH;
  const bf16x8 aq0 = cvt8(*(const float4*)(qrow + q * 8),
                          *(const float4*)(qrow + q * 8 + 4));
  const bf16x8 aq1 = cvt8(*(const float4*)(qrow + 32 + q * 8),
                          *(const float4*)(qrow + 32 + q * 8 + 4));

  // Staging lane constants: issue0 rows 0..31, issue1 rows 32..63; physical
  // slot lane&7 holds logical chunk (lane&7)^(row&7), row&7 = lane>>3.
  const int srow0 = wu * 8 + (lane >> 3);
  const int scol = (lane & 7) ^ (lane >> 3);

  const short* kbase_h = Kb + h * DKH;
  const short* vbase_h = Vt + (((size_t)h * DKH) << 9);

#define STG1(g0, rs, buf, tslot)                                          \
  {                                                                       \
    async_cp16((g0) + (size_t)srow0 * (rs) + scol * 8,                    \
               &Stage[buf][(tslot) * 4096 + wu * 512]);                   \
    async_cp16((g0) + (size_t)(srow0 + 32) * (rs) + scol * 8,             \
               &Stage[buf][(tslot) * 4096 + (4 + wu) * 512]);             \
  }
#define KTILE(c, j0) (kbase_h + ((size_t)((c) * SEQ) + (j0)) * DMODEL)
#define VTILE(c, j0) (vbase_h + (((size_t)((c) * NHEAD * DKH)) << 9) + (j0))

  f32x4 acc[4][4] = {};          // R@V partials [c][nt] — static idx only
  float sacc[2][4], ebb[2][4];

  // prologue: stage K c0,c1 of jt=0 into buf 0
  STG1(KTILE(0, 0), DMODEL, 0, 0);
  STG1(KTILE(1, 0), DMODEL, 0, 1);

  for (int jt = 0; jt < 8; ++jt) {
    const int j0 = jt * 64;
    bf16x8 ar;  // R A-fragment for this jt (loaded at ph2==2)
#pragma unroll
    for (int ph2 = 0; ph2 < 4; ++ph2) {
      __syncthreads();  // drains stage(jt,ph2); frees buf (ph2^1)
      const int buf = ph2 & 1, nbuf = buf ^ 1;
      // ---- stage next phase (overlaps this phase's compute) ----
      if (ph2 == 0) {
        STG1(KTILE(2, j0), DMODEL, nbuf, 0);
        STG1(KTILE(3, j0), DMODEL, nbuf, 1);
      } else if (ph2 == 1) {
        STG1(VTILE(0, j0), SEQ, nbuf, 0);
        STG1(VTILE(1, j0), SEQ, nbuf, 1);
      } else if (ph2 == 2) {
        STG1(VTILE(2, j0), SEQ, nbuf, 0);
        STG1(VTILE(3, j0), SEQ, nbuf, 1);
      } else if (jt < 7) {
        STG1(KTILE(0, j0 + 64), DMODEL, nbuf, 0);
        STG1(KTILE(1, j0 + 64), DMODEL, nbuf, 1);
      }
      if (ph2 < 2) {
        // ---- QK^T for c = ph2*2, ph2*2+1 (compile-time) ----
        if (ph2 == 0) {
#pragma unroll
          for (int t = 0; t < 2; ++t)
#pragma unroll
            for (int r = 0; r < 4; ++r) { sacc[t][r] = 0.0f; ebb[t][r] = 0.0f; }
        }
#pragma unroll
        for (int ct = 0; ct < 2; ++ct) {
          const int c = ph2 * 2 + ct;
          const short* S = &Stage[buf][ct * 4096];
#pragma unroll
          for (int ntl = 0; ntl < 2; ++ntl) {
            const int row = (wj * 2 + ntl) * 16 + l15;
            const int p0 = q ^ (l15 & 7);
            bf16x8 b0 = *(const bf16x8*)&S[row * 64 + p0 * 8];
            bf16x8 b1 = *(const bf16x8*)&S[row * 64 + (p0 ^ 4) * 8];
            f32x4 s = {};
            s = __builtin_amdgcn_mfma_f32_16x16x32_bf16(aq0, b0, s, 0, 0, 0);
            s = __builtin_amdgcn_mfma_f32_16x16x32_bf16(aq1, b1, s, 0, 0, 0);
#pragma unroll
            for (int r = 0; r < 4; ++r) {
              const float e = __expf(s[r]);
              sacc[ntl][r] += e;
              ebb[ntl][r] = (c == b) ? e : ebb[ntl][r];
            }
          }
        }
        if (ph2 == 1) {  // fenmu complete -> R tile (bf16)
#pragma unroll
          for (int ntl = 0; ntl < 2; ++ntl)
#pragma unroll
            for (int r = 0; r < 4; ++r)
              Rs[wi * 16 + q * 4 + r][(wj * 2 + ntl) * 16 + l15] =
                  f2bf(ebb[ntl][r] / (8.0f * sacc[ntl][r]));
        }
      } else {
        // ---- R@V partial for c = (ph2-2)*2 + ct (compile-time) ----
        if (ph2 == 2) ar = *(const bf16x8*)&Rs[wi * 16 + l15][wj * 32 + q * 8];
#pragma unroll
        for (int ct = 0; ct < 2; ++ct) {
          const int c = (ph2 - 2) * 2 + ct;
          const short* S = &Stage[buf][ct * 4096];
#pragma unroll
          for (int nt = 0; nt < 4; ++nt) {
            const int row = nt * 16 + l15;
            const int pb = (wj * 4 + q) ^ (l15 & 7);
            bf16x8 bv = *(const bf16x8*)&S[row * 64 + pb * 8];
            acc[c][nt] = __builtin_amdgcn_mfma_f32_16x16x32_bf16(
                ar, bv, acc[c][nt], 0, 0, 0);
          }
        }
      }
    }
  }
#undef STG1
#undef KTILE
#undef VTILE

  // ---- cross-wj score reduction (K-halves) into wj==0 waves ----
#pragma unroll
  for (int c = 0; c < BSZ; ++c) {
    if (wj == 1) {
#pragma unroll
      for (int nt = 0; nt < 4; ++nt)
#pragma unroll
        for (int r = 0; r < 4; ++r)
          xch[(nt * 4 + r) * 128 + wi * 64 + lane] = acc[c][nt][r];
    }
    __syncthreads();
    if (wj == 0) {
#pragma unroll
      for (int nt = 0; nt < 4; ++nt)
#pragma unroll
        for (int r = 0; r < 4; ++r)
          acc[c][nt][r] += xch[(nt * 4 + r) * 128 + wi * 64 + lane];
    }
    __syncthreads();
  }

  if (wj == 0) {
    float al[4], be[4];
#pragma unroll
    for (int nt = 0; nt < 4; ++nt) {
      al[nt] = alpha[nt * 16 + l15];
      be[nt] = beta[nt * 16 + l15];
    }
    float hacc[4][4] = {};  // [r][nt]
#pragma unroll
    for (int c = 0; c < BSZ; ++c) {
#pragma unroll
      for (int r = 0; r < 4; ++r) {
        float e0 = __expf(acc[c][0][r]), e1 = __expf(acc[c][1][r]);
        float e2 = __expf(acc[c][2][r]), e3 = __expf(acc[c][3][r]);
        float es = e0 + e1 + e2 + e3;
#pragma unroll
        for (int m = 8; m >= 1; m >>= 1) es += __shfl_xor(es, m);
        const float inv = 1.0f / es;
        const float d0 = e0 * inv - 0.015625f, d1 = e1 * inv - 0.015625f;
        const float d2 = e2 * inv - 0.015625f, d3 = e3 * inv - 0.015625f;
        float sq = d0 * d0 + d1 * d1 + d2 * d2 + d3 * d3;
#pragma unroll
        for (int m = 8; m >= 1; m >>= 1) sq += __shfl_xor(sq, m);
        const float rs = 1.0f / (sqrtf(sq * (1.0f / 63.0f)) + EPSLN);
        hacc[r][0] += al[0] * d0 * rs + be[0];
        hacc[r][1] += al[1] * d1 * rs + be[1];
        hacc[r][2] += al[2] * d2 * rs + be[2];
        hacc[r][3] += al[3] * d3 * rs + be[3];
      }
    }
#pragma unroll
    for (int r = 0; r < 4; ++r) {
      const size_t rowoff =
          (size_t)(b * SEQ + i0 + wi * 16 + q * 4 + r) * DMODEL + h * DKH;
#pragma unroll
      for (int nt = 0; nt < 4; ++nt) {
        const int d = nt * 16 + l15;
        const float o = hacc[r][nt] + 4.0f * Qp[rowoff + d];
        Hc[rowoff + d] = f2bf(o);
      }
    }
  }
}

// ---------------------------------------------------------------------------
extern "C" void kernel_launch(void* const* d_in, const int* in_sizes, int n_in,
                              void* d_out, int out_size, void* d_ws,
                              size_t ws_size, hipStream_t stream) {
  (void)in_sizes; (void)n_in; (void)out_size; (void)ws_size;
  const float* q = (const float*)d_in[0];
  const float* k = (const float*)d_in[1];
  const float* v = (const float*)d_in[2];
  const float* Wq = (const float*)d_in[3];
  const float* bq = (const float*)d_in[4];
  const float* Wk = (const float*)d_in[5];
  const float* bk = (const float*)d_in[6];
  const float* Wv = (const float*)d_in[7];
  const float* bv = (const float*)d_in[8];
  const float* Wo = (const float*)d_in[9];
  const float* bo = (const float*)d_in[10];
  const float* alpha = (const float*)d_in[11];
  const float* beta = (const float*)d_in[12];
  float* out = (float*)d_out;

  char* wsb = (char*)d_ws;
  short* qb = (short*)(wsb);
  short* kb = (short*)(wsb + (2u << 20));
  short* vb = (short*)(wsb + (4u << 20));
  float* Qp = (float*)(wsb + (6u << 20));
  short* Kb = (short*)(wsb + (10u << 20));
  short* Vtg = (short*)(wsb + (12u << 20));
  short* Hc = (short*)(wsb + (14u << 20));
  short* Wqt = (short*)(wsb + (16u << 20));
  short* Wkt = (short*)(wsb + (16u << 20) + (512u << 10));
  short* Wvt = (short*)(wsb + (17u << 20));
  short* Wot = (short*)(wsb + (17u << 20) + (512u << 10));

  prep_kernel<<<dim3(1792), 256, 0, stream>>>(q, k, v, qb, kb, vb,
                                              Wq, Wk, Wv, Wo,
                                              Wqt, Wkt, Wvt, Wot);
  proj_gemm<<<dim3(4, 16, 3), 256, 0, stream>>>(qb, kb, vb, Wqt, Wkt, Wvt,
                                                bq, bk, bv, Qp, Kb, Vtg);
  attn2_kernel<<<dim3(512), 256, 0, stream>>>(Qp, Kb, Vtg, alpha, beta, Hc);
  out_gemm<<<dim3(4, 16), 256, 0, stream>>>(Hc, Wot, bo, out);
}

// Round 9
// 141.968 us; speedup vs baseline: 1.0902x; 1.0364x over previous
//
#include <hip/hip_runtime.h>
#include <hip/hip_bf16.h>

// Problem constants (fixed by the reference).
#define BSZ 4
#define SEQ 512
#define DMODEL 512
#define NHEAD 8
#define DKH 64
#define EPSLN 1e-6f

typedef short bf16x8 __attribute__((ext_vector_type(8)));
typedef float f32x4 __attribute__((ext_vector_type(4)));

// fp32 -> bf16 round-to-nearest-even
static __device__ __forceinline__ short f2bf(float x) {
  unsigned u = __builtin_bit_cast(unsigned, x);
  u = (u + 0x7FFFu + ((u >> 16) & 1u)) >> 16;
  return (short)u;
}
static __device__ __forceinline__ bf16x8 cvt8(float4 a, float4 b) {
  bf16x8 r;
  r[0] = f2bf(a.x); r[1] = f2bf(a.y); r[2] = f2bf(a.z); r[3] = f2bf(a.w);
  r[4] = f2bf(b.x); r[5] = f2bf(b.y); r[6] = f2bf(b.z); r[7] = f2bf(b.w);
  return r;
}
static __device__ __forceinline__ unsigned pk2(float a, float b) {
  return (unsigned)(unsigned short)f2bf(a) |
         ((unsigned)(unsigned short)f2bf(b) << 16);
}
// async 16B/lane global -> LDS (lds dest = wave-uniform base + lane*16)
static __device__ __forceinline__ void async_cp16(const void* g, void* l) {
  __builtin_amdgcn_global_load_lds(
      (const __attribute__((address_space(1))) unsigned int*)g,
      (__attribute__((address_space(3))) unsigned int*)l, 16, 0, 0);
}

// ---------------------------------------------------------------------------
// Prep (one launch): blocks 0..1535 cast q/k/v fp32->bf16; blocks 1536..1791
// transpose+cast the four W's to bf16 [N][K].
// ---------------------------------------------------------------------------
__global__ __launch_bounds__(256) void prep_kernel(
    const float* __restrict__ q, const float* __restrict__ k,
    const float* __restrict__ v, short* __restrict__ qb,
    short* __restrict__ kb, short* __restrict__ vb,
    const float* __restrict__ Wq, const float* __restrict__ Wk,
    const float* __restrict__ Wv, const float* __restrict__ Wo,
    short* __restrict__ Wqt, short* __restrict__ Wkt,
    short* __restrict__ Wvt, short* __restrict__ Wot) {
  __shared__ float T[64][65];
  const int bx = blockIdx.x;
  if (bx < 1536) {
    const int which = bx >> 9, blk = bx & 511;
    const float* s; short* d;
    switch (which) {
      case 0: s = q; d = qb; break;
      case 1: s = k; d = kb; break;
      default: s = v; d = vb; break;
    }
    const size_t idx = (size_t)blk * 2048 + (size_t)threadIdx.x * 8;
    float4 a = *(const float4*)&s[idx];
    float4 b = *(const float4*)&s[idx + 4];
    *(bf16x8*)&d[idx] = cvt8(a, b);
    return;
  }
  const int r = bx - 1536;
  const int mat = r >> 6, m = r & 63;
  const int k0 = (m & 7) * 64, n0 = (m >> 3) * 64;
  const float* src; short* dst;
  switch (mat) {
    case 0: src = Wq; dst = Wqt; break;
    case 1: src = Wk; dst = Wkt; break;
    case 2: src = Wv; dst = Wvt; break;
    default: src = Wo; dst = Wot; break;
  }
  const int tid = threadIdx.x;
  const int n4 = (tid & 15) * 4, kk = tid >> 4;
#pragma unroll
  for (int p = 0; p < 4; ++p) {
    float4 w4 = *(const float4*)&src[(size_t)(k0 + kk + p * 16) * DMODEL + n0 + n4];
    T[kk + p * 16][n4 + 0] = w4.x;
    T[kk + p * 16][n4 + 1] = w4.y;
    T[kk + p * 16][n4 + 2] = w4.z;
    T[kk + p * 16][n4 + 3] = w4.w;
  }
  __syncthreads();
  const int k4 = (tid & 15) * 4;
#pragma unroll
  for (int p = 0; p < 4; ++p) {
    const int nn = (tid >> 4) + p * 16;
    float x0 = T[k4 + 0][nn], x1 = T[k4 + 1][nn];
    float x2 = T[k4 + 2][nn], x3 = T[k4 + 3][nn];
    uint2 u; u.x = pk2(x0, x1); u.y = pk2(x2, x3);
    *(uint2*)&dst[(size_t)(n0 + nn) * DMODEL + k0 + k4] = u;
  }
}

// ---------------------------------------------------------------------------
// m97-style GEMM body (R8: swizzled LDS chunks, conflict-free frag reads).
// ---------------------------------------------------------------------------
__device__ __forceinline__ void gemm_body(
    const short* __restrict__ A, const short* __restrict__ Wt,
    const float* __restrict__ bias, void* __restrict__ out, int omode) {
  __shared__ short As[2][128 * 32];
  __shared__ short Bs[2][128 * 32];
  const int tid = threadIdx.x;
  const int w = tid >> 6, lane = tid & 63;
  const int l15 = lane & 15, q = lane >> 4;
  const int wm = w >> 1, wn = w & 1;
  const int bn = blockIdx.x * 128, bm = blockIdx.y * 128;
  const int wu = __builtin_amdgcn_readfirstlane(w);
  const int srow = wu * 16 + (lane >> 2);
  const int sch = (lane & 3) ^ ((srow >> 1) & 3);

  f32x4 acc[4][4] = {};

#define GSTAGE(k0, buf)                                                      \
  {                                                                          \
    const short* ga0 = A + (size_t)(bm + srow) * 512 + (k0) + sch * 8;       \
    const short* ga1 = A + (size_t)(bm + srow + 64) * 512 + (k0) + sch * 8;  \
    const short* gb0 = Wt + (size_t)(bn + srow) * 512 + (k0) + sch * 8;      \
    const short* gb1 = Wt + (size_t)(bn + srow + 64) * 512 + (k0) + sch * 8; \
    async_cp16(ga0, &As[buf][wu * 512]);                                     \
    async_cp16(ga1, &As[buf][(4 + wu) * 512]);                               \
    async_cp16(gb0, &Bs[buf][wu * 512]);                                     \
    async_cp16(gb1, &Bs[buf][(4 + wu) * 512]);                               \
  }

  GSTAGE(0, 0);
  for (int ks = 0; ks < 16; ++ks) {
    __syncthreads();
    if (ks < 15) GSTAGE((ks + 1) * 32, (ks + 1) & 1);
    const short* a = As[ks & 1];
    const short* bsh = Bs[ks & 1];
    bf16x8 af[4], bfr[4];
#pragma unroll
    for (int mt = 0; mt < 4; ++mt) {
      const int ra = wm * 64 + mt * 16 + l15;
      af[mt] = *(const bf16x8*)&a[ra * 32 + (q ^ ((ra >> 1) & 3)) * 8];
    }
#pragma unroll
    for (int nt = 0; nt < 4; ++nt) {
      const int rb = wn * 64 + nt * 16 + l15;
      bfr[nt] = *(const bf16x8*)&bsh[rb * 32 + (q ^ ((rb >> 1) & 3)) * 8];
    }
#pragma unroll
    for (int mt = 0; mt < 4; ++mt)
#pragma unroll
      for (int nt = 0; nt < 4; ++nt)
        acc[mt][nt] = __builtin_amdgcn_mfma_f32_16x16x32_bf16(
            af[mt], bfr[nt], acc[mt][nt], 0, 0, 0);
  }
#undef GSTAGE

  float bv[4];
#pragma unroll
  for (int nt = 0; nt < 4; ++nt) bv[nt] = bias[bn + wn * 64 + nt * 16 + l15];
#pragma unroll
  for (int mt = 0; mt < 4; ++mt)
#pragma unroll
    for (int nt = 0; nt < 4; ++nt) {
      const int col = bn + wn * 64 + nt * 16 + l15;
#pragma unroll
      for (int r = 0; r < 4; ++r) {
        const int row = bm + wm * 64 + mt * 16 + q * 4 + r;
        const float val = acc[mt][nt][r] + bv[nt];
        if (omode == 0) {
          ((float*)out)[(size_t)row * 512 + col] = val;
        } else if (omode == 1) {
          ((short*)out)[(size_t)row * 512 + col] = f2bf(val);
        } else {
          const int cc = row >> 9, j = row & 511;
          const int hh = col >> 6, d = col & 63;
          ((short*)out)[(((size_t)(cc * 8 + hh) * 64 + d) << 9) + j] = f2bf(val);
        }
      }
    }
}

__global__ __launch_bounds__(256, 3) void proj_gemm(
    const short* qb, const short* kb, const short* vb,
    const short* Wqt, const short* Wkt, const short* Wvt,
    const float* bq, const float* bk, const float* bvs,
    float* Qp, short* Kb, short* Vt) {
  const short* A; const short* Wt; const float* bias; void* out; int omode;
  switch (blockIdx.z) {
    case 0: A = qb; Wt = Wqt; bias = bq; out = Qp; omode = 0; break;
    case 1: A = kb; Wt = Wkt; bias = bk; out = Kb; omode = 1; break;
    default: A = vb; Wt = Wvt; bias = bvs; out = Vt; omode = 2; break;
  }
  gemm_body(A, Wt, bias, out, omode);
}

__global__ __launch_bounds__(256, 3) void out_gemm(
    const short* Hc, const short* Wot, const float* bo, float* out) {
  gemm_body(Hc, Wot, bo, out, 0);
}

// ---------------------------------------------------------------------------
// Fused attention v4 — barrier-free main loop (AITER-style fine vmcnt).
// Block = (b,h,32 i-rows), 512 blocks, 4 waves. Wave w privately owns
// j-columns {jt*64 + w*16 + 0..15}. Main loop = 32 wave-private 4KB tiles
// (per j-pair t: K c0..3 [32j x 64d], then R->Rsw, then V c0..3 [64d x 32j]),
// staged into a per-wave 2-slot ring via global_load_lds; sync is
// s_waitcnt vmcnt(4) on the wave's OWN loads — loads stay in flight, no
// __syncthreads until the epilogue. exp/fenmu in regs; R round-trip through
// wave-private Rsw (stride 40 = bank-balanced). Epilogue: 3 static-indexed
// cross-wave reduction rounds (ring LDS reused), LN per wave (c=w),
// cooperative 4-way sum + 4*qh residual -> bf16 Hc.
// All register arrays statically indexed (R3 lesson). ~210 VGPR -> (256,2).
// LDS: ring 32K + Rsw 10K = 42K.
// ---------------------------------------------------------------------------
__global__ __launch_bounds__(256, 2) void attn4_kernel(
    const float* __restrict__ Qp, const short* __restrict__ Kb,
    const short* __restrict__ Vt, const float* __restrict__ alpha,
    const float* __restrict__ beta, short* __restrict__ Hc) {
  __shared__ __align__(16) short Ring[4][2][2048];   // per-wave 2 x 4KB
  __shared__ __align__(16) short Rsw[4][32 * 40];    // per-wave R tile

  const int bx = blockIdx.x;
  const int h = bx & 7;
  const int b = (bx >> 3) & 3;
  const int it = bx >> 5;
  const int i0 = it * 32;
  const int tid = threadIdx.x;
  const int w = tid >> 6, lane = tid & 63;
  const int l15 = lane & 15, q = lane >> 4;
  const int wu = __builtin_amdgcn_readfirstlane(w);
  short* ring0 = &Ring[wu][0][0];
  short* ring1 = &Ring[wu][1][0];
  short* rsw = &Rsw[wu][0];

  // Q A-fragments for 32 i-rows (2 m-tiles), reused throughout.
  bf16x8 aq[2][2];
#pragma unroll
  for (int mi = 0; mi < 2; ++mi) {
    const float* qrow =
        Qp + (size_t)(b * SEQ + i0 + mi * 16 + l15) * DMODEL + h * DKH;
    aq[mi][0] = cvt8(*(const float4*)(qrow + q * 8),
                     *(const float4*)(qrow + q * 8 + 4));
    aq[mi][1] = cvt8(*(const float4*)(qrow + 32 + q * 8),
                     *(const float4*)(qrow + 32 + q * 8 + 4));
  }

  // Per-lane staging source offsets (shorts). K tile (32j x 64d):
  // issue s, lane l: row r = s*8 + (l>>3), phys chunk l&7 holds logical
  // (l&7)^(r&7) with r&7 == l>>3. V pair tile (64d x 32j): row d =
  // s*16 + (l>>2), phys chunk l&3 holds logical (l&3)^((d>>1)&3), with
  // (d>>1)&3 == (l>>3)&3; logical L -> j-sub L>>1, j-offset (L&1)*8.
  const int scol = (lane & 7) ^ (lane >> 3);
  int koff[4], voff[4];
#pragma unroll
  for (int s = 0; s < 4; ++s) {
    koff[s] = ((s >> 1) * 64 + w * 16 + (s & 1) * 8 + (lane >> 3)) * 512 +
              h * 64 + scol * 8;
    const int Lc = (lane & 3) ^ ((lane >> 3) & 3);
    voff[s] = h * 32768 + (s * 16 + (lane >> 2)) * 512 + w * 16 +
              (Lc >> 1) * 64 + (Lc & 1) * 8;
  }

#define STAGEK(t, c, sp)                                             \
  do {                                                               \
    const short* gK = Kb + (c) * 262144 + (t) * 65536;               \
    async_cp16(gK + koff[0], (sp));                                  \
    async_cp16(gK + koff[1], (sp) + 512);                            \
    async_cp16(gK + koff[2], (sp) + 1024);                           \
    async_cp16(gK + koff[3], (sp) + 1536);                           \
  } while (0)
#define STAGEV(t, c, sp)                                             \
  do {                                                               \
    const short* gV = Vt + (c) * 262144 + (t) * 128;                 \
    async_cp16(gV + voff[0], (sp));                                  \
    async_cp16(gV + voff[1], (sp) + 512);                            \
    async_cp16(gV + voff[2], (sp) + 1024);                           \
    async_cp16(gV + voff[3], (sp) + 1536);                           \
  } while (0)

  f32x4 acc[4][2][4] = {};  // [c][mi][nt] — static indices only
  STAGEK(0, 0, ring0);      // prologue: tile (t=0, ph=0)

  for (int t = 0; t < 4; ++t) {
    float sacc[2][2][4], ebb[2][2][4];  // [sub][mi][r]
    bf16x8 ar[2];
#pragma unroll
    for (int ph = 0; ph < 8; ++ph) {
      short* cur = (ph & 1) ? ring1 : ring0;
      short* nxt = (ph & 1) ? ring0 : ring1;
      // stage next tile (stays in flight across compute; no barrier)
      if (ph < 3) {
        STAGEK(t, ph + 1, nxt);
      } else if (ph == 3) {
        STAGEV(t, 0, nxt);
      } else if (ph < 7) {
        STAGEV(t, ph - 3, nxt);
      } else if (t < 3) {
        STAGEK(t + 1, 0, nxt);
      }
      if (ph == 7 && t == 3) {
        asm volatile("s_waitcnt vmcnt(0)" ::: "memory");
      } else {
        asm volatile("s_waitcnt vmcnt(4)" ::: "memory");
      }
      if (ph < 4) {
        const int c = ph;  // static
        if (ph == 0) {
#pragma unroll
          for (int s2 = 0; s2 < 2; ++s2)
#pragma unroll
            for (int mi = 0; mi < 2; ++mi)
#pragma unroll
              for (int r = 0; r < 4; ++r) {
                sacc[s2][mi][r] = 0.0f;
                ebb[s2][mi][r] = 0.0f;
              }
        }
#pragma unroll
        for (int sub = 0; sub < 2; ++sub) {
          const int row = sub * 16 + l15;
          const int p0 = q ^ (l15 & 7);
          bf16x8 b0 = *(const bf16x8*)&cur[row * 64 + p0 * 8];
          bf16x8 b1 = *(const bf16x8*)&cur[row * 64 + (p0 ^ 4) * 8];
          f32x4 s0 = {}, s1 = {};
          s0 = __builtin_amdgcn_mfma_f32_16x16x32_bf16(aq[0][0], b0, s0, 0, 0, 0);
          s0 = __builtin_amdgcn_mfma_f32_16x16x32_bf16(aq[0][1], b1, s0, 0, 0, 0);
          s1 = __builtin_amdgcn_mfma_f32_16x16x32_bf16(aq[1][0], b0, s1, 0, 0, 0);
          s1 = __builtin_amdgcn_mfma_f32_16x16x32_bf16(aq[1][1], b1, s1, 0, 0, 0);
#pragma unroll
          for (int r = 0; r < 4; ++r) {
            const float e0 = __expf(s0[r]);
            const float e1 = __expf(s1[r]);
            sacc[sub][0][r] += e0;
            sacc[sub][1][r] += e1;
            ebb[sub][0][r] = (c == b) ? e0 : ebb[sub][0][r];
            ebb[sub][1][r] = (c == b) ? e1 : ebb[sub][1][r];
          }
        }
        if (ph == 3) {  // fenmu complete -> R tile (wave-private)
#pragma unroll
          for (int sub = 0; sub < 2; ++sub)
#pragma unroll
            for (int mi = 0; mi < 2; ++mi)
#pragma unroll
              for (int r = 0; r < 4; ++r)
                rsw[(mi * 16 + q * 4 + r) * 40 + sub * 16 + l15] =
                    f2bf(ebb[sub][mi][r] / (8.0f * sacc[sub][mi][r]));
        }
      } else {
        const int c = ph - 4;  // static
        if (ph == 4) {
          ar[0] = *(const bf16x8*)&rsw[(0 * 16 + l15) * 40 + q * 8];
          ar[1] = *(const bf16x8*)&rsw[(1 * 16 + l15) * 40 + q * 8];
        }
#pragma unroll
        for (int nt = 0; nt < 4; ++nt) {
          const int d = nt * 16 + l15;
          const int pv = q ^ ((l15 >> 1) & 3);
          bf16x8 bvv = *(const bf16x8*)&cur[d * 32 + pv * 8];
          acc[c][0][nt] = __builtin_amdgcn_mfma_f32_16x16x32_bf16(
              ar[0], bvv, acc[c][0][nt], 0, 0, 0);
          acc[c][1][nt] = __builtin_amdgcn_mfma_f32_16x16x32_bf16(
              ar[1], bvv, acc[c][1][nt], 0, 0, 0);
        }
      }
    }
  }
#undef STAGEK
#undef STAGEV

  // ---------------- epilogue (barriers OK here) ----------------
  float* xch = (float*)&Ring[0][0][0];  // 4 regions x 2048 floats (ring reuse)
#define XWR(A, reg)                                                        \
  do {                                                                     \
    _Pragma("unroll") for (int mi = 0; mi < 2; ++mi)                       \
        _Pragma("unroll") for (int nt = 0; nt < 4; ++nt)                   \
        *(f32x4*)&xch[(reg) * 2048 + (mi * 4 + nt) * 256 + lane * 4] =     \
            A[mi][nt];                                                     \
  } while (0)
#define XADD(A, reg)                                                       \
  do {                                                                     \
    _Pragma("unroll") for (int mi = 0; mi < 2; ++mi)                       \
        _Pragma("unroll") for (int nt = 0; nt < 4; ++nt) {                 \
      f32x4 o =                                                            \
          *(f32x4*)&xch[(reg) * 2048 + (mi * 4 + nt) * 256 + lane * 4];    \
      A[mi][nt] += o;                                                      \
    }                                                                      \
  } while (0)

  __syncthreads();  // all waves done with ring
#pragma unroll
  for (int k = 1; k < 4; ++k) {
    if (w == 0) XWR(acc[(0 + k) & 3], (0 + k) & 3);
    else if (w == 1) XWR(acc[(1 + k) & 3], (1 + k) & 3);
    else if (w == 2) XWR(acc[(2 + k) & 3], (2 + k) & 3);
    else XWR(acc[(3 + k) & 3], (3 + k) & 3);
    __syncthreads();
    if (w == 0) XADD(acc[0], 0);
    else if (w == 1) XADD(acc[1], 1);
    else if (w == 2) XADD(acc[2], 2);
    else XADD(acc[3], 3);
    __syncthreads();
  }
#undef XWR
#undef XADD

  // wave w now holds full scores for c = w: copy to sc (static branches).
  f32x4 sc[2][4];
  if (w == 0) {
#pragma unroll
    for (int mi = 0; mi < 2; ++mi)
#pragma unroll
      for (int nt = 0; nt < 4; ++nt) sc[mi][nt] = acc[0][mi][nt];
  } else if (w == 1) {
#pragma unroll
    for (int mi = 0; mi < 2; ++mi)
#pragma unroll
      for (int nt = 0; nt < 4; ++nt) sc[mi][nt] = acc[1][mi][nt];
  } else if (w == 2) {
#pragma unroll
    for (int mi = 0; mi < 2; ++mi)
#pragma unroll
      for (int nt = 0; nt < 4; ++nt) sc[mi][nt] = acc[2][mi][nt];
  } else {
#pragma unroll
    for (int mi = 0; mi < 2; ++mi)
#pragma unroll
      for (int nt = 0; nt < 4; ++nt) sc[mi][nt] = acc[3][mi][nt];
  }

  // softmax(d=64) + LN for c=w; write LN output to region w.
  {
    float al[4], be[4];
#pragma unroll
    for (int nt = 0; nt < 4; ++nt) {
      al[nt] = alpha[nt * 16 + l15];
      be[nt] = beta[nt * 16 + l15];
    }
#pragma unroll
    for (int mi = 0; mi < 2; ++mi)
#pragma unroll
      for (int r = 0; r < 4; ++r) {
        float e0 = __expf(sc[mi][0][r]), e1 = __expf(sc[mi][1][r]);
        float e2 = __expf(sc[mi][2][r]), e3 = __expf(sc[mi][3][r]);
        float es = e0 + e1 + e2 + e3;
#pragma unroll
        for (int m = 8; m >= 1; m >>= 1) es += __shfl_xor(es, m);
        const float inv = 1.0f / es;
        const float d0 = e0 * inv - 0.015625f, d1 = e1 * inv - 0.015625f;
        const float d2 = e2 * inv - 0.015625f, d3 = e3 * inv - 0.015625f;
        float sq = d0 * d0 + d1 * d1 + d2 * d2 + d3 * d3;
#pragma unroll
        for (int m = 8; m >= 1; m >>= 1) sq += __shfl_xor(sq, m);
        const float rs = 1.0f / (sqrtf(sq * (1.0f / 63.0f)) + EPSLN);
        const int i = mi * 16 + q * 4 + r;
        float* o = &xch[w * 2048 + i * 64 + l15];
        o[0] = al[0] * d0 * rs + be[0];
        o[16] = al[1] * d1 * rs + be[1];
        o[32] = al[2] * d2 * rs + be[2];
        o[48] = al[3] * d3 * rs + be[3];
      }
  }
  __syncthreads();

  // cooperative final sum over the 4 LN outputs + 4*qh residual -> Hc.
  {
    const int i2 = tid >> 3, d8 = (tid & 7) * 8;
    f32x4 sA = {}, sB = {};
#pragma unroll
    for (int reg = 0; reg < 4; ++reg) {
      sA += *(f32x4*)&xch[reg * 2048 + i2 * 64 + d8];
      sB += *(f32x4*)&xch[reg * 2048 + i2 * 64 + d8 + 4];
    }
    const size_t rowoff = (size_t)(b * SEQ + i0 + i2) * DMODEL + h * DKH + d8;
    float4 q0 = *(const float4*)&Qp[rowoff];
    float4 q1 = *(const float4*)&Qp[rowoff + 4];
    float4 a, bb;
    a.x = sA[0] + 4.0f * q0.x; a.y = sA[1] + 4.0f * q0.y;
    a.z = sA[2] + 4.0f * q0.z; a.w = sA[3] + 4.0f * q0.w;
    bb.x = sB[0] + 4.0f * q1.x; bb.y = sB[1] + 4.0f * q1.y;
    bb.z = sB[2] + 4.0f * q1.z; bb.w = sB[3] + 4.0f * q1.w;
    *(bf16x8*)&Hc[rowoff] = cvt8(a, bb);
  }
}

// ---------------------------------------------------------------------------
extern "C" void kernel_launch(void* const* d_in, const int* in_sizes, int n_in,
                              void* d_out, int out_size, void* d_ws,
                              size_t ws_size, hipStream_t stream) {
  (void)in_sizes; (void)n_in; (void)out_size; (void)ws_size;
  const float* q = (const float*)d_in[0];
  const float* k = (const float*)d_in[1];
  const float* v = (const float*)d_in[2];
  const float* Wq = (const float*)d_in[3];
  const float* bq = (const float*)d_in[4];
  const float* Wk = (const float*)d_in[5];
  const float* bk = (const float*)d_in[6];
  const float* Wv = (const float*)d_in[7];
  const float* bv = (const float*)d_in[8];
  const float* Wo = (const float*)d_in[9];
  const float* bo = (const float*)d_in[10];
  const float* alpha = (const float*)d_in[11];
  const float* beta = (const float*)d_in[12];
  float* out = (float*)d_out;

  char* wsb = (char*)d_ws;
  short* qb = (short*)(wsb);
  short* kb = (short*)(wsb + (2u << 20));
  short* vb = (short*)(wsb + (4u << 20));
  float* Qp = (float*)(wsb + (6u << 20));
  short* Kb = (short*)(wsb + (10u << 20));
  short* Vtg = (short*)(wsb + (12u << 20));
  short* Hc = (short*)(wsb + (14u << 20));
  short* Wqt = (short*)(wsb + (16u << 20));
  short* Wkt = (short*)(wsb + (16u << 20) + (512u << 10));
  short* Wvt = (short*)(wsb + (17u << 20));
  short* Wot = (short*)(wsb + (17u << 20) + (512u << 10));

  prep_kernel<<<dim3(1792), 256, 0, stream>>>(q, k, v, qb, kb, vb,
                                              Wq, Wk, Wv, Wo,
                                              Wqt, Wkt, Wvt, Wot);
  proj_gemm<<<dim3(4, 16, 3), 256, 0, stream>>>(qb, kb, vb, Wqt, Wkt, Wvt,
                                                bq, bk, bv, Qp, Kb, Vtg);
  attn4_kernel<<<dim3(512), 256, 0, stream>>>(Qp, Kb, Vtg, alpha, beta, Hc);
  out_gemm<<<dim3(4, 16), 256, 0, stream>>>(Hc, Wot, bo, out);
}